// Round 5
// baseline (222.852 us; speedup 1.0000x reference)
//
#include <hip/hip_runtime.h>
#include <hip/hip_bf16.h>

#define BF __hip_bfloat16

// B=16, C=64, H=128, W=128, MX=MY=24, HIDDEN=32
// fp32 in/out; intermediates bf16.
//
// Workspace (bf16 units, peak 7471104 = 14.94 MB, unchanged):
//   gB1 [0,6144)        k_fwd GEMM1 B-table   (dead after k_fwd; S overwrites)
//   gB2 [6144,18432)    k_fwd GEMM2 B-table   (dead after k_fwd)
//   Xr  [6291456,6881280)  [xy][bc]           (dead after k_mix)
//   Xi  [6881280,7471104)
//   Sr  [0,589824)      [bo][xy]              (overwrites gB1/gB2, legal)
//   Si  [589824,1179648)
//   Pr  [1179648,4325376)  [bo][u][y]
//   Pi  [4325376,7471104)  (aliases X; X dead after k_mix)
//
// R9 (passed, 223 us): k_fused 62 us, upstream ~161.
// R10: k_fused GEMMs transposed to D[o-rows][v-cols] (swap MFMA operand
// roles; operand frag layouts are symmetric for 16x16x32). Epilogue store
// becomes v-contiguous: 4x64B segments/instr instead of 64x4B scatter
// (~16x fewer store transactions; est. ~25 us of k_fused's 62 was store
// scatter).  Twiddle build: __cosf/__sinf only (was sincos + discard).
// Other kernels byte-identical to R9.

typedef __attribute__((ext_vector_type(8))) short s8b;    // 8 bf16 (4 VGPRs)
typedef __attribute__((ext_vector_type(4))) float f32x4;  // MFMA acc

__device__ __forceinline__ float erf_fast(float x) {
    // Abramowitz-Stegun 7.1.26, |eps| <= 1.5e-7
    float ax = fabsf(x);
    float t  = 1.0f / (1.0f + 0.3275911f * ax);
    float p  = t * (0.254829592f + t * (-0.284496736f + t * (1.421413741f
             + t * (-1.453152027f + t * 1.061405429f))));
    float r  = 1.0f - p * __expf(-ax * ax);
    return copysignf(r, x);
}
__device__ __forceinline__ float geluf(float v) {
    return 0.5f * v * (1.0f + erf_fast(v * 0.7071067811865476f));
}
__device__ __forceinline__ float bf2f(BF v) { return __bfloat162float(v); }
__device__ __forceinline__ short f2bs(float f) {
    union { BF h; short s; } u; u.h = __float2bfloat16(f); return u.s;
}
// build bf16x8 B-fragment from 8 consecutive fp32 (row-major [col][k] weights)
__device__ __forceinline__ s8b ld8f(const float* __restrict__ p) {
    float4 a = *(const float4*)p;
    float4 b = *(const float4*)(p + 4);
    s8b r;
    r[0] = f2bs(a.x); r[1] = f2bs(a.y); r[2] = f2bs(a.z); r[3] = f2bs(a.w);
    r[4] = f2bs(b.x); r[5] = f2bs(b.y); r[6] = f2bs(b.z); r[7] = f2bs(b.w);
    return r;
}

// ---------------------------------------------------------------------------
// k_tw: fill k_fwd's twiddle B-tables. gB1[48][128], gB2[48][256].
// ---------------------------------------------------------------------------
__global__ __launch_bounds__(256) void k_tw(BF* __restrict__ gB1,
                                            BF* __restrict__ gB2) {
    int idx = blockIdx.x * 256 + threadIdx.x;
    if (idx < 6144) {                       // gB1[y'][v]
        int y = idx >> 7, v = idx & 127;
        int yy = (y < 24) ? y : y - 24;
        int r = (v * yy) & 127;
        float s, c; __sincosf((float)r * 0.04908738521234052f, &s, &c);
        gB1[idx] = __float2bfloat16(y < 24 ? c : -s);
    } else {                                // gB2[x'][k]: k<128 u=k; k>=128 u=k-128
        int j = idx - 6144;
        int xp = j >> 8, k = j & 255;
        int u = k & 127, half = k >> 7;
        int x = (xp < 24) ? xp : xp - 24;
        int r = (u * x) & 127;
        float s, c; __sincosf((float)r * 0.04908738521234052f, &s, &c);
        float val = (xp < 24) ? (half ? s : c) : (half ? c : -s);
        gB2[j] = __float2bfloat16(val);
    }
}

// ---------------------------------------------------------------------------
// k_fwd: both forward DFTs for one bc, on MFMA.  B-frags from global tables
// (L1/L2 resident).  LDS = Tl only (13 KB).
// ---------------------------------------------------------------------------
__global__ __launch_bounds__(256) void k_fwd(const float* __restrict__ x,
                                             const BF* __restrict__ gB1,
                                             const BF* __restrict__ gB2,
                                             BF* __restrict__ XrB,
                                             BF* __restrict__ XiB) {
    __shared__ __align__(16) short Tl[48 * 136];

    const int tid  = threadIdx.x;
    const int bc   = blockIdx.x;
    const int lane = tid & 63;
    const int wv   = tid >> 6;
    const int lr   = lane & 15;
    const int lg   = lane >> 4;

    // ---- GEMM1: M=128 (u, wave wv rows wv*32..+32), N=48, K=128.
    {
        const float* xb = x + ((size_t)bc << 14);
        s8b af[2][4];
        #pragma unroll
        for (int m = 0; m < 2; ++m) {
            const int u = wv * 32 + m * 16 + lr;
            #pragma unroll
            for (int s = 0; s < 4; ++s)
                af[m][s] = ld8f(xb + (size_t)u * 128 + s * 32 + lg * 8);
        }
        f32x4 acc[2][3];
        #pragma unroll
        for (int m = 0; m < 2; ++m)
            #pragma unroll
            for (int n = 0; n < 3; ++n)
                #pragma unroll
                for (int r = 0; r < 4; ++r) acc[m][n][r] = 0.f;
        #pragma unroll
        for (int s = 0; s < 4; ++s)
            #pragma unroll
            for (int n = 0; n < 3; ++n) {
                s8b bfr = *(const s8b*)((const short*)gB1 + (n * 16 + lr) * 128 + s * 32 + lg * 8);
                #pragma unroll
                for (int m = 0; m < 2; ++m)
                    acc[m][n] = __builtin_amdgcn_mfma_f32_16x16x32_bf16(af[m][s], bfr, acc[m][n], 0, 0, 0);
            }
        #pragma unroll
        for (int m = 0; m < 2; ++m) {
            const int u0 = wv * 32 + m * 16 + lg * 4;
            #pragma unroll
            for (int n = 0; n < 3; ++n) {
                short4 t;
                t.x = f2bs(acc[m][n][0]); t.y = f2bs(acc[m][n][1]);
                t.z = f2bs(acc[m][n][2]); t.w = f2bs(acc[m][n][3]);
                *(short4*)&Tl[(n * 16 + lr) * 136 + u0] = t;
            }
        }
    }
    __syncthreads();

    // ---- GEMM2: M=24 (y, pad 32), N=48, K=256 (Tr 0..127, Ti 128..255).
    for (int j = wv; j < 6; j += 4) {
        const int m = j / 3, n = j % 3;
        const int y  = m * 16 + lr;
        const int r1 = (y < 24) ? y      : 0;
        const int r2 = (y < 24) ? y + 24 : 0;
        f32x4 acc = {0.f, 0.f, 0.f, 0.f};
        #pragma unroll
        for (int s = 0; s < 8; ++s) {
            s8b a = *(const s8b*)&Tl[((s < 4) ? r1 : r2) * 136 + (s & 3) * 32 + lg * 8];
            s8b b = *(const s8b*)((const short*)gB2 + (n * 16 + lr) * 256 + s * 32 + lg * 8);
            acc = __builtin_amdgcn_mfma_f32_16x16x32_bf16(a, b, acc, 0, 0, 0);
        }
        const int col = n * 16 + lr;
        const int xc  = (col < 24) ? col : col - 24;
        BF* dst = (col < 24) ? XrB : XiB;
        #pragma unroll
        for (int r = 0; r < 4; ++r) {
            const int yo = m * 16 + lg * 4 + r;
            if (yo < 24)
                dst[(size_t)(xc * 24 + yo) * 1024 + bc] = __float2bfloat16(acc[r]);
        }
    }
}

// ---------------------------------------------------------------------------
// k_mix (MFMA): per-mode complex channel mix.  Block = xy (576), 256 thr.
// ---------------------------------------------------------------------------
__global__ __launch_bounds__(256) void k_mix(const float* __restrict__ wr_g,
                                             const float* __restrict__ wi_g,
                                             const BF* __restrict__ XrB,
                                             const BF* __restrict__ XiB,
                                             BF* __restrict__ SrB,
                                             BF* __restrict__ SiB) {
    __shared__ __align__(16) short Br[64 * 136], Bi[64 * 136];
    const int tid  = threadIdx.x;
    const int xy   = blockIdx.x;
    const int lane = tid & 63;
    const int wv   = tid >> 6;
    const int lr   = lane & 15;
    const int lg   = lane >> 4;

    const float* wrp = wr_g + ((size_t)xy << 12);
    const float* wip = wi_g + ((size_t)xy << 12);
    for (int i = tid; i < 4096; i += 256) {
        int c = i >> 6, o = i & 63;
        float vr = wrp[i], vi = wip[i];
        short br = f2bs(vr), bi = f2bs(vi), nbi = f2bs(-vi);
        Br[o * 136 + c]      = br;
        Br[o * 136 + 64 + c] = nbi;
        Bi[o * 136 + c]      = bi;
        Bi[o * 136 + 64 + c] = br;
    }

    // A-frags: A[b=lr][k]: k<64 Xr[c=k], k>=64 Xi[c=k-64]
    s8b az[4];
    {
        const short* xr = (const short*)XrB + ((size_t)xy << 10) + lr * 64;
        const short* xi = (const short*)XiB + ((size_t)xy << 10) + lr * 64;
        #pragma unroll
        for (int s = 0; s < 2; ++s) {
            az[s]     = *(const s8b*)(xr + s * 32 + lg * 8);
            az[s + 2] = *(const s8b*)(xi + s * 32 + lg * 8);
        }
    }
    __syncthreads();

    f32x4 ar = {0.f, 0.f, 0.f, 0.f}, ai = {0.f, 0.f, 0.f, 0.f};
    #pragma unroll
    for (int s = 0; s < 4; ++s) {
        s8b brf = *(const s8b*)&Br[(wv * 16 + lr) * 136 + s * 32 + lg * 8];
        ar = __builtin_amdgcn_mfma_f32_16x16x32_bf16(az[s], brf, ar, 0, 0, 0);
    }
    #pragma unroll
    for (int s = 0; s < 4; ++s) {
        s8b bif = *(const s8b*)&Bi[(wv * 16 + lr) * 136 + s * 32 + lg * 8];
        ai = __builtin_amdgcn_mfma_f32_16x16x32_bf16(az[s], bif, ai, 0, 0, 0);
    }

    const int o = wv * 16 + lr;
    #pragma unroll
    for (int r = 0; r < 4; ++r) {
        int b = lg * 4 + r;
        size_t base = (size_t)((b << 6) + o) * 576 + xy;
        SrB[base] = __float2bfloat16(ar[r]);
        SiB[base] = __float2bfloat16(ai[r]);
    }
}

// ---------------------------------------------------------------------------
// k_invP (MFMA): inverse H-transform.  Block = bo (1024), 256 thr, 4 waves.
// ---------------------------------------------------------------------------
__global__ __launch_bounds__(256) void k_invP(const BF* __restrict__ SrB,
                                              const BF* __restrict__ SiB,
                                              BF* __restrict__ PrB,
                                              BF* __restrict__ PiB) {
    __shared__ __align__(16) short Bp[48 * 72];   // 6.9 KB, write-once
    const int tid  = threadIdx.x;
    const int bo   = blockIdx.x;
    const int lane = tid & 63;
    const int wv   = tid >> 6;
    const int lr   = lane & 15;
    const int lg   = lane >> 4;
    const float inv = 6.103515625e-05f;   // 1/16384

    for (int i = tid; i < 576; i += 256) {
        int x = i / 24, y = i - x * 24;
        float sr = bf2f(SrB[(size_t)bo * 576 + i]);
        float si = bf2f(SiB[(size_t)bo * 576 + i]);
        float sc = (y == 0) ? inv : 2.0f * inv;
        Bp[y * 72 + x]             = f2bs(sc * sr);
        Bp[y * 72 + 24 + x]        = f2bs(-sc * si);
        Bp[(24 + y) * 72 + x]      = f2bs((y == 0) ? 0.f : sc * si);
        Bp[(24 + y) * 72 + 24 + x] = f2bs((y == 0) ? 0.f : sc * sr);
    }
    for (int i = tid; i < 768; i += 256)          // zero K-pad [48,64)
        Bp[(i >> 4) * 72 + 48 + (i & 15)] = 0;

    // A twiddles in registers (32 sincos/thread)
    s8b a[2][2];
    #pragma unroll
    for (int m = 0; m < 2; ++m) {
        const int u = wv * 32 + m * 16 + lr;
        #pragma unroll
        for (int s = 0; s < 2; ++s) {
            #pragma unroll
            for (int j = 0; j < 8; ++j) {
                const int k = s * 32 + lg * 8 + j;
                float val = 0.f;
                if (k < 48) {
                    int x = (k < 24) ? k : k - 24;
                    int r = (u * x) & 127;
                    float sn, cs;
                    __sincosf((float)r * 0.04908738521234052f, &sn, &cs);
                    val = (k < 24) ? cs : sn;
                }
                a[m][s][j] = f2bs(val);
            }
        }
    }
    __syncthreads();

    #pragma unroll
    for (int m = 0; m < 2; ++m)
        #pragma unroll
        for (int n = 0; n < 3; ++n) {
            f32x4 acc = {0.f, 0.f, 0.f, 0.f};
            #pragma unroll
            for (int s = 0; s < 2; ++s) {
                s8b bfr = *(const s8b*)&Bp[(n * 16 + lr) * 72 + s * 32 + lg * 8];
                acc = __builtin_amdgcn_mfma_f32_16x16x32_bf16(a[m][s], bfr, acc, 0, 0, 0);
            }
            const int col = n * 16 + lr;
            BF* dst = (col < 24) ? PrB : PiB;
            const int y = (col < 24) ? col : col - 24;
            #pragma unroll
            for (int r = 0; r < 4; ++r) {
                const int u = wv * 32 + m * 16 + lg * 4 + r;
                dst[(size_t)bo * 3072 + (size_t)u * 24 + y] = __float2bfloat16(acc[r]);
            }
        }
}

// ---------------------------------------------------------------------------
// k_fused (MFMA, transposed orientation): inverse W-transform + skip + GELU +
// MLP + soft-gate.  Block = (b, u): 2048 blocks, 256 thr = 4 waves; wave wv
// owns pixel cols v in [wv*32, wv*32+32).  All GEMMs D[o-rows][v-cols]:
//   A = weight/P rows (row idx via lr), B = x/twiddle/H1/Z cols (col idx via
//   lr), D element (row = mt*16+lg*4+reg, col = nt*16+lr).  Epilogue stores
//   are v-contiguous: 4x64B segments per instruction.
// LDS (disjoint, write-once): Plds[64][72], H1s[v][o] [128][72],
// Zls[v][kh] [128][40] = 37.9 KB, 4 blocks/CU.
// ---------------------------------------------------------------------------
__global__ __launch_bounds__(256) void k_fused(const float* __restrict__ x,
                                               const BF* __restrict__ PrB,
                                               const BF* __restrict__ PiB,
                                               const float* __restrict__ wsk,
                                               const float* __restrict__ w1,
                                               const float* __restrict__ b1,
                                               const float* __restrict__ w2,
                                               const float* __restrict__ b2,
                                               const float* __restrict__ gt,
                                               float* __restrict__ out) {
    __shared__ __align__(16) short Plds[64 * 72];    // P^T [o][k]
    __shared__ __align__(16) short H1s[128 * 72];    // h1 bf16 [v][o]
    __shared__ __align__(16) short Zls[128 * 40];    // z  bf16 [v][kh]

    const int tid  = threadIdx.x;
    const int b    = blockIdx.x >> 7;
    const int u    = blockIdx.x & 127;
    const int lane = tid & 63;
    const int wv   = tid >> 6;     // wave id: v-cols [wv*32, wv*32+32)
    const int lr   = lane & 15;
    const int lg   = lane >> 4;
    const int vb   = wv * 32;      // wave v-base

    // ---- stage P^T (unchanged from R9)
    {
        const size_t pb = (size_t)(b * 64) * 3072 + (size_t)u * 24;
        for (int i = tid; i < 1536; i += 256) {
            int o = i / 24, y = i - o * 24;
            size_t g = pb + (size_t)o * 3072 + y;
            Plds[o * 72 + y]      = *(const short*)&PrB[g];
            Plds[o * 72 + 24 + y] = *(const short*)&PiB[g];
        }
        for (int i = tid; i < 1024; i += 256)
            Plds[(i >> 4) * 72 + 48 + (i & 15)] = 0;
    }

    // ---- x B-frags (cols = v): bx[nv][s][j] = x[b][c=s*32+lg*8+j][u][v]
    s8b bx[2][2];
    {
        const float* xb = x + (size_t)(b * 64) * 16384 + (size_t)u * 128;
        #pragma unroll
        for (int nv = 0; nv < 2; ++nv) {
            const int v = vb + nv * 16 + lr;
            #pragma unroll
            for (int s = 0; s < 2; ++s)
                #pragma unroll
                for (int j = 0; j < 8; ++j)
                    bx[nv][s][j] = f2bs(xb[(size_t)(s * 32 + lg * 8 + j) * 16384 + v]);
        }
    }

    // ---- twiddle B-frags: tw[k<24][v]=cos(vk th), tw[24..48)[v]=-sin, pad 0
    s8b btw[2][2];
    #pragma unroll
    for (int nv = 0; nv < 2; ++nv) {
        const int v = vb + nv * 16 + lr;
        #pragma unroll
        for (int s = 0; s < 2; ++s) {
            #pragma unroll
            for (int j = 0; j < 8; ++j) {
                const int k = s * 32 + lg * 8 + j;
                float val = 0.f;
                if (k < 24) {
                    int r = (v * k) & 127;
                    val = __cosf((float)r * 0.04908738521234052f);
                } else if (k < 48) {
                    int r = (v * (k - 24)) & 127;
                    val = -__sinf((float)r * 0.04908738521234052f);
                }
                btw[nv][s][j] = f2bs(val);
            }
        }
    }
    __syncthreads();   // Plds staged

    // ---- GEMM 1+2: spec + skip, D[o][v]
    f32x4 acc[4][2];
    #pragma unroll
    for (int mo = 0; mo < 4; ++mo)
        #pragma unroll
        for (int nv = 0; nv < 2; ++nv)
            #pragma unroll
            for (int r = 0; r < 4; ++r) acc[mo][nv][r] = 0.f;

    #pragma unroll
    for (int s = 0; s < 2; ++s)
        #pragma unroll
        for (int mo = 0; mo < 4; ++mo) {
            s8b ap = *(const s8b*)&Plds[(mo * 16 + lr) * 72 + s * 32 + lg * 8];
            #pragma unroll
            for (int nv = 0; nv < 2; ++nv)
                acc[mo][nv] = __builtin_amdgcn_mfma_f32_16x16x32_bf16(ap, btw[nv][s], acc[mo][nv], 0, 0, 0);
        }
    #pragma unroll
    for (int s = 0; s < 2; ++s)
        #pragma unroll
        for (int mo = 0; mo < 4; ++mo) {
            s8b aw = ld8f(wsk + (mo * 16 + lr) * 64 + s * 32 + lg * 8);
            #pragma unroll
            for (int nv = 0; nv < 2; ++nv)
                acc[mo][nv] = __builtin_amdgcn_mfma_f32_16x16x32_bf16(aw, bx[nv][s], acc[mo][nv], 0, 0, 0);
        }

    // ---- h1 = gelu(acc): element (o = mo*16+lg*4+r, v = vb+nv*16+lr)
    f32x4 h1r[4][2];
    #pragma unroll
    for (int mo = 0; mo < 4; ++mo)
        #pragma unroll
        for (int nv = 0; nv < 2; ++nv)
            #pragma unroll
            for (int r = 0; r < 4; ++r) {
                float h = geluf(acc[mo][nv][r]);
                h1r[mo][nv][r] = h;
                H1s[(vb + nv * 16 + lr) * 72 + mo * 16 + lg * 4 + r] = f2bs(h);
            }
    __syncthreads();   // H1 complete

    // ---- fc1: z^T[kh][v] = gelu(w1 @ h1^T + b1), M=32 kh (2 tiles), K=64 o
    f32x4 zac[2][2];
    #pragma unroll
    for (int mk = 0; mk < 2; ++mk)
        #pragma unroll
        for (int nv = 0; nv < 2; ++nv)
            #pragma unroll
            for (int r = 0; r < 4; ++r) zac[mk][nv][r] = 0.f;
    #pragma unroll
    for (int s = 0; s < 2; ++s) {
        s8b bh[2];
        #pragma unroll
        for (int nv = 0; nv < 2; ++nv)
            bh[nv] = *(const s8b*)&H1s[(vb + nv * 16 + lr) * 72 + s * 32 + lg * 8];
        #pragma unroll
        for (int mk = 0; mk < 2; ++mk) {
            s8b aw = ld8f(w1 + (mk * 16 + lr) * 64 + s * 32 + lg * 8);
            #pragma unroll
            for (int nv = 0; nv < 2; ++nv)
                zac[mk][nv] = __builtin_amdgcn_mfma_f32_16x16x32_bf16(aw, bh[nv], zac[mk][nv], 0, 0, 0);
        }
    }
    #pragma unroll
    for (int mk = 0; mk < 2; ++mk)
        #pragma unroll
        for (int r = 0; r < 4; ++r) {
            const float bb = b1[mk * 16 + lg * 4 + r];
            #pragma unroll
            for (int nv = 0; nv < 2; ++nv)
                Zls[(vb + nv * 16 + lr) * 40 + mk * 16 + lg * 4 + r] =
                    f2bs(geluf(zac[mk][nv][r] + bb));
        }
    __syncthreads();   // Zl complete

    // ---- fc2: out[o][v] = w2 @ z^T + b2 + gate*h1, K=32 (1 step)
    f32x4 oac[4][2];
    #pragma unroll
    for (int mo = 0; mo < 4; ++mo)
        #pragma unroll
        for (int nv = 0; nv < 2; ++nv)
            #pragma unroll
            for (int r = 0; r < 4; ++r) oac[mo][nv][r] = 0.f;
    s8b bz[2];
    #pragma unroll
    for (int nv = 0; nv < 2; ++nv)
        bz[nv] = *(const s8b*)&Zls[(vb + nv * 16 + lr) * 40 + lg * 8];
    #pragma unroll
    for (int mo = 0; mo < 4; ++mo) {
        s8b aw = ld8f(w2 + (mo * 16 + lr) * 32 + lg * 8);
        #pragma unroll
        for (int nv = 0; nv < 2; ++nv)
            oac[mo][nv] = __builtin_amdgcn_mfma_f32_16x16x32_bf16(aw, bz[nv], oac[mo][nv], 0, 0, 0);
    }

    // ---- epilogue: v-contiguous stores (16 consecutive fp32 per lr-group)
    float* ob = out + (size_t)(b * 64) * 16384 + (size_t)u * 128;
    #pragma unroll
    for (int mo = 0; mo < 4; ++mo)
        #pragma unroll
        for (int r = 0; r < 4; ++r) {
            const int o = mo * 16 + lg * 4 + r;
            const float b2v = b2[o];
            const float gv  = gt[o];
            #pragma unroll
            for (int nv = 0; nv < 2; ++nv)
                ob[(size_t)o * 16384 + vb + nv * 16 + lr] =
                    oac[mo][nv][r] + b2v + gv * h1r[mo][nv][r];
        }
}

// ---------------------------------------------------------------------------
extern "C" void kernel_launch(void* const* d_in, const int* in_sizes, int n_in,
                              void* d_out, int out_size, void* d_ws, size_t ws_size,
                              hipStream_t stream) {
    (void)in_sizes; (void)n_in; (void)out_size; (void)ws_size;
    const float* x   = (const float*)d_in[0];
    const float* wr  = (const float*)d_in[1];
    const float* wi  = (const float*)d_in[2];
    const float* wsk = (const float*)d_in[3];
    const float* w1  = (const float*)d_in[4];
    const float* b1  = (const float*)d_in[5];
    const float* w2  = (const float*)d_in[6];
    const float* b2  = (const float*)d_in[7];
    const float* gt  = (const float*)d_in[8];

    BF* wsB = (BF*)d_ws;
    BF* gB1 = wsB;                 // [0, 6144)          dead after k_fwd
    BF* gB2 = wsB + 6144;          // [6144, 18432)      dead after k_fwd
    BF* Xr  = wsB + 6291456;       // [6291456, 6881280)
    BF* Xi  = wsB + 6881280;       // [6881280, 7471104)
    BF* Sr  = wsB;                 // [0, 589824)  overwrites gB1/gB2 (legal)
    BF* Si  = wsB + 589824;
    BF* Pr  = wsB + 1179648;       // [1179648, 4325376)
    BF* Pi  = wsB + 4325376;       // [4325376, 7471104) aliases X (X dead)
    // peak footprint: 7471104 bf16 = 14.94 MB (unchanged)

    hipLaunchKernelGGL(k_tw,   dim3(72),   dim3(256), 0, stream, gB1, gB2);
    hipLaunchKernelGGL(k_fwd,  dim3(1024), dim3(256), 0, stream, x, gB1, gB2, Xr, Xi);
    hipLaunchKernelGGL(k_mix,  dim3(576),  dim3(256), 0, stream, wr, wi, Xr, Xi, Sr, Si);
    hipLaunchKernelGGL(k_invP, dim3(1024), dim3(256), 0, stream, Sr, Si, Pr, Pi);
    hipLaunchKernelGGL(k_fused, dim3(2048), dim3(256), 0, stream,
                       x, Pr, Pi, wsk, w1, b1, w2, b2, gt, (float*)d_out);
}

// Round 6
// 211.595 us; speedup vs baseline: 1.0532x; 1.0532x over previous
//
#include <hip/hip_runtime.h>
#include <hip/hip_bf16.h>

#define BF __hip_bfloat16

// B=16, C=64, H=128, W=128, MX=MY=24, HIDDEN=32
// fp32 in/out; intermediates bf16.
//
// Workspace (bf16 units, peak 7364608 <= 7471104 budget):
//   gB1 [0,6144)           k_fwd GEMM1 B-table (dead after k_fwd; S overwrites)
//   gB2 [6144,18432)       k_fwd GEMM2 B-table
//   Sr  [0,589824)         [bo][xy]    (k_mix out, overwrites gB1/gB2: legal)
//   Si  [589824,1179648)
//   Pr  [1179648,4325376)  [bo][u][24y]
//   Pi  [4325376,7340032)  [bo][u][23y] (y=1..23; y=0 identically 0) aliases X
//   Xr  [6160384,6750208)  [xy][bc]    (dead after k_mix; Pi overwrites)
//   Xi  [6750208,7340032)
//   gTw [7340032,7348224)  [v][64k] k_fused twiddle frags   (live whole run)
//   gTa [7348224,7356416)  [u][64k] k_invP twiddle frags
//   wkB [7356416,7360512)  bf16 wsk [o][c]
//   w1B [7360512,7362560)  bf16 w1  [kh][c]
//   w2B [7362560,7364608)  bf16 w2  [o][kh]
//
// R10 (passed, 223 us): store-transpose was NEUTRAL -> k_fused is NOT
// store-bound; it is VALU/latency-bound on block-invariant conversions
// (32 sincos + ~256 weight cvts per thread, identical across 2048 blocks).
// R11: hoist ALL block-invariant cvt work into k_tw tables (twiddle frag
// tables gTw/gTa = one 16B load per frag; bf16 weight tables). Pi stored
// without the always-zero y=0 plane to free table space. k_mix: stage W
// plain [o][c] (half the LDS writes, 34->18 KB), negate Xi in-register.
// k_fwd byte-identical (launcher pointers only).

typedef __attribute__((ext_vector_type(8))) short s8b;    // 8 bf16 (4 VGPRs)
typedef __attribute__((ext_vector_type(4))) float f32x4;  // MFMA acc

__device__ __forceinline__ float erf_fast(float x) {
    // Abramowitz-Stegun 7.1.26, |eps| <= 1.5e-7
    float ax = fabsf(x);
    float t  = 1.0f / (1.0f + 0.3275911f * ax);
    float p  = t * (0.254829592f + t * (-0.284496736f + t * (1.421413741f
             + t * (-1.453152027f + t * 1.061405429f))));
    float r  = 1.0f - p * __expf(-ax * ax);
    return copysignf(r, x);
}
__device__ __forceinline__ float geluf(float v) {
    return 0.5f * v * (1.0f + erf_fast(v * 0.7071067811865476f));
}
__device__ __forceinline__ float bf2f(BF v) { return __bfloat162float(v); }
__device__ __forceinline__ short f2bs(float f) {
    union { BF h; short s; } u; u.h = __float2bfloat16(f); return u.s;
}
// build bf16x8 B-fragment from 8 consecutive fp32
__device__ __forceinline__ s8b ld8f(const float* __restrict__ p) {
    float4 a = *(const float4*)p;
    float4 b = *(const float4*)(p + 4);
    s8b r;
    r[0] = f2bs(a.x); r[1] = f2bs(a.y); r[2] = f2bs(a.z); r[3] = f2bs(a.w);
    r[4] = f2bs(b.x); r[5] = f2bs(b.y); r[6] = f2bs(b.z); r[7] = f2bs(b.w);
    return r;
}

// ---------------------------------------------------------------------------
// k_tw: all precomputed tables.  43008 elements, grid 168 x 256.
// ---------------------------------------------------------------------------
__global__ __launch_bounds__(256) void k_tw(const float* __restrict__ wsk,
                                            const float* __restrict__ w1,
                                            const float* __restrict__ w2,
                                            BF* __restrict__ gB1,
                                            BF* __restrict__ gB2,
                                            BF* __restrict__ gTw,
                                            BF* __restrict__ gTa,
                                            BF* __restrict__ wkB,
                                            BF* __restrict__ w1B,
                                            BF* __restrict__ w2B) {
    const int idx = blockIdx.x * 256 + threadIdx.x;
    const float th = 0.04908738521234052f;   // 2*pi/128
    if (idx < 6144) {                        // gB1[y'][v]
        int y = idx >> 7, v = idx & 127;
        int yy = (y < 24) ? y : y - 24;
        int r = (v * yy) & 127;
        float s, c; __sincosf((float)r * th, &s, &c);
        gB1[idx] = __float2bfloat16(y < 24 ? c : -s);
    } else if (idx < 18432) {                // gB2[x'][k]
        int j = idx - 6144;
        int xp = j >> 8, k = j & 255;
        int u = k & 127, half = k >> 7;
        int x = (xp < 24) ? xp : xp - 24;
        int r = (u * x) & 127;
        float s, c; __sincosf((float)r * th, &s, &c);
        float val = (xp < 24) ? (half ? s : c) : (half ? c : -s);
        gB2[j] = __float2bfloat16(val);
    } else if (idx < 26624) {                // gTw[v][k]: k<24 cos, 24..47 -sin, pad 0
        int j = idx - 18432;
        int v = j >> 6, k = j & 63;
        float val = 0.f;
        if (k < 24)      val =  __cosf((float)((v * k) & 127) * th);
        else if (k < 48) val = -__sinf((float)((v * (k - 24)) & 127) * th);
        gTw[j] = __float2bfloat16(val);
    } else if (idx < 34816) {                // gTa[u][k]: k<24 cos, 24..47 +sin, pad 0
        int j = idx - 26624;
        int u = j >> 6, k = j & 63;
        float val = 0.f;
        if (k < 24)      val = __cosf((float)((u * k) & 127) * th);
        else if (k < 48) val = __sinf((float)((u * (k - 24)) & 127) * th);
        gTa[j] = __float2bfloat16(val);
    } else if (idx < 38912) {                // wkB = bf16(wsk), [o][c] row-major
        int j = idx - 34816;
        wkB[j] = __float2bfloat16(wsk[j]);
    } else if (idx < 40960) {                // w1B = bf16(w1), [kh][c]
        int j = idx - 38912;
        w1B[j] = __float2bfloat16(w1[j]);
    } else if (idx < 43008) {                // w2B = bf16(w2), [o][kh]
        int j = idx - 40960;
        w2B[j] = __float2bfloat16(w2[j]);
    }
}

// ---------------------------------------------------------------------------
// k_fwd: both forward DFTs for one bc, on MFMA.  (byte-identical to R10)
// ---------------------------------------------------------------------------
__global__ __launch_bounds__(256) void k_fwd(const float* __restrict__ x,
                                             const BF* __restrict__ gB1,
                                             const BF* __restrict__ gB2,
                                             BF* __restrict__ XrB,
                                             BF* __restrict__ XiB) {
    __shared__ __align__(16) short Tl[48 * 136];

    const int tid  = threadIdx.x;
    const int bc   = blockIdx.x;
    const int lane = tid & 63;
    const int wv   = tid >> 6;
    const int lr   = lane & 15;
    const int lg   = lane >> 4;

    // ---- GEMM1: M=128 (u, wave wv rows wv*32..+32), N=48, K=128.
    {
        const float* xb = x + ((size_t)bc << 14);
        s8b af[2][4];
        #pragma unroll
        for (int m = 0; m < 2; ++m) {
            const int u = wv * 32 + m * 16 + lr;
            #pragma unroll
            for (int s = 0; s < 4; ++s)
                af[m][s] = ld8f(xb + (size_t)u * 128 + s * 32 + lg * 8);
        }
        f32x4 acc[2][3];
        #pragma unroll
        for (int m = 0; m < 2; ++m)
            #pragma unroll
            for (int n = 0; n < 3; ++n)
                #pragma unroll
                for (int r = 0; r < 4; ++r) acc[m][n][r] = 0.f;
        #pragma unroll
        for (int s = 0; s < 4; ++s)
            #pragma unroll
            for (int n = 0; n < 3; ++n) {
                s8b bfr = *(const s8b*)((const short*)gB1 + (n * 16 + lr) * 128 + s * 32 + lg * 8);
                #pragma unroll
                for (int m = 0; m < 2; ++m)
                    acc[m][n] = __builtin_amdgcn_mfma_f32_16x16x32_bf16(af[m][s], bfr, acc[m][n], 0, 0, 0);
            }
        #pragma unroll
        for (int m = 0; m < 2; ++m) {
            const int u0 = wv * 32 + m * 16 + lg * 4;
            #pragma unroll
            for (int n = 0; n < 3; ++n) {
                short4 t;
                t.x = f2bs(acc[m][n][0]); t.y = f2bs(acc[m][n][1]);
                t.z = f2bs(acc[m][n][2]); t.w = f2bs(acc[m][n][3]);
                *(short4*)&Tl[(n * 16 + lr) * 136 + u0] = t;
            }
        }
    }
    __syncthreads();

    // ---- GEMM2: M=24 (y, pad 32), N=48, K=256 (Tr 0..127, Ti 128..255).
    for (int j = wv; j < 6; j += 4) {
        const int m = j / 3, n = j % 3;
        const int y  = m * 16 + lr;
        const int r1 = (y < 24) ? y      : 0;
        const int r2 = (y < 24) ? y + 24 : 0;
        f32x4 acc = {0.f, 0.f, 0.f, 0.f};
        #pragma unroll
        for (int s = 0; s < 8; ++s) {
            s8b a = *(const s8b*)&Tl[((s < 4) ? r1 : r2) * 136 + (s & 3) * 32 + lg * 8];
            s8b b = *(const s8b*)((const short*)gB2 + (n * 16 + lr) * 256 + s * 32 + lg * 8);
            acc = __builtin_amdgcn_mfma_f32_16x16x32_bf16(a, b, acc, 0, 0, 0);
        }
        const int col = n * 16 + lr;
        const int xc  = (col < 24) ? col : col - 24;
        BF* dst = (col < 24) ? XrB : XiB;
        #pragma unroll
        for (int r = 0; r < 4; ++r) {
            const int yo = m * 16 + lg * 4 + r;
            if (yo < 24)
                dst[(size_t)(xc * 24 + yo) * 1024 + bc] = __float2bfloat16(acc[r]);
        }
    }
}

// ---------------------------------------------------------------------------
// k_mix (MFMA): per-mode complex channel mix.  Block = xy (576), 256 thr.
//   Sr = Xr@Wr + (-Xi)@Wi ; Si = Xr@Wi + Xi@Wr   (K=64 each, 8 MFMA total)
//   Wr/Wi staged plain [o][c] bf16 (pad 72; 144 B row = 16B-aligned).
//   Xi negated in-register (sign-bit XOR on bf16).
// ---------------------------------------------------------------------------
__global__ __launch_bounds__(256) void k_mix(const float* __restrict__ wr_g,
                                             const float* __restrict__ wi_g,
                                             const BF* __restrict__ XrB,
                                             const BF* __restrict__ XiB,
                                             BF* __restrict__ SrB,
                                             BF* __restrict__ SiB) {
    __shared__ __align__(16) short Br[64 * 72], Bi[64 * 72];   // [o][c]
    const int tid  = threadIdx.x;
    const int xy   = blockIdx.x;
    const int lane = tid & 63;
    const int wv   = tid >> 6;
    const int lr   = lane & 15;
    const int lg   = lane >> 4;

    const float* wrp = wr_g + ((size_t)xy << 12);
    const float* wip = wi_g + ((size_t)xy << 12);
    for (int i = tid; i < 4096; i += 256) {
        int c = i >> 6, o = i & 63;
        Br[o * 72 + c] = f2bs(wrp[i]);
        Bi[o * 72 + c] = f2bs(wip[i]);
    }

    // A-frags: rows b = lr, k = c (0..63).  Xr, Xi, and -Xi.
    s8b axr[2], axi[2], axin[2];
    {
        const short* xr = (const short*)XrB + ((size_t)xy << 10) + lr * 64;
        const short* xi = (const short*)XiB + ((size_t)xy << 10) + lr * 64;
        #pragma unroll
        for (int s = 0; s < 2; ++s) {
            axr[s] = *(const s8b*)(xr + s * 32 + lg * 8);
            axi[s] = *(const s8b*)(xi + s * 32 + lg * 8);
            #pragma unroll
            for (int j = 0; j < 8; ++j)
                axin[s][j] = axi[s][j] ^ (short)0x8000;
        }
    }
    __syncthreads();

    f32x4 ar = {0.f, 0.f, 0.f, 0.f}, ai = {0.f, 0.f, 0.f, 0.f};
    #pragma unroll
    for (int s = 0; s < 2; ++s) {
        s8b wrf = *(const s8b*)&Br[(wv * 16 + lr) * 72 + s * 32 + lg * 8];
        s8b wif = *(const s8b*)&Bi[(wv * 16 + lr) * 72 + s * 32 + lg * 8];
        ar = __builtin_amdgcn_mfma_f32_16x16x32_bf16(axr[s],  wrf, ar, 0, 0, 0);
        ar = __builtin_amdgcn_mfma_f32_16x16x32_bf16(axin[s], wif, ar, 0, 0, 0);
        ai = __builtin_amdgcn_mfma_f32_16x16x32_bf16(axr[s],  wif, ai, 0, 0, 0);
        ai = __builtin_amdgcn_mfma_f32_16x16x32_bf16(axi[s],  wrf, ai, 0, 0, 0);
    }

    const int o = wv * 16 + lr;
    #pragma unroll
    for (int r = 0; r < 4; ++r) {
        int b = lg * 4 + r;
        size_t base = (size_t)((b << 6) + o) * 576 + xy;
        SrB[base] = __float2bfloat16(ar[r]);
        SiB[base] = __float2bfloat16(ai[r]);
    }
}

// ---------------------------------------------------------------------------
// k_invP (MFMA): inverse H-transform.  Block = bo (1024), 256 thr, 4 waves.
// A-twiddle frags from gTa table (one 16B load each).  Pi stored [u][23]
// (y=1..23; y=0 is identically zero and skipped).
// ---------------------------------------------------------------------------
__global__ __launch_bounds__(256) void k_invP(const BF* __restrict__ SrB,
                                              const BF* __restrict__ SiB,
                                              const BF* __restrict__ gTa,
                                              BF* __restrict__ PrB,
                                              BF* __restrict__ PiB) {
    __shared__ __align__(16) short Bp[48 * 72];   // 6.9 KB, write-once
    const int tid  = threadIdx.x;
    const int bo   = blockIdx.x;
    const int lane = tid & 63;
    const int wv   = tid >> 6;
    const int lr   = lane & 15;
    const int lg   = lane >> 4;
    const float inv = 6.103515625e-05f;   // 1/16384

    for (int i = tid; i < 576; i += 256) {
        int x = i / 24, y = i - x * 24;
        float sr = bf2f(SrB[(size_t)bo * 576 + i]);
        float si = bf2f(SiB[(size_t)bo * 576 + i]);
        float sc = (y == 0) ? inv : 2.0f * inv;
        Bp[y * 72 + x]             = f2bs(sc * sr);
        Bp[y * 72 + 24 + x]        = f2bs(-sc * si);
        Bp[(24 + y) * 72 + x]      = f2bs((y == 0) ? 0.f : sc * si);
        Bp[(24 + y) * 72 + 24 + x] = f2bs((y == 0) ? 0.f : sc * sr);
    }
    for (int i = tid; i < 768; i += 256)          // zero K-pad [48,64)
        Bp[(i >> 4) * 72 + 48 + (i & 15)] = 0;

    // A twiddle frags from table (replaces 32 sincos chains)
    s8b a[2][2];
    {
        const short* gta = (const short*)gTa;
        #pragma unroll
        for (int m = 0; m < 2; ++m) {
            const int u = wv * 32 + m * 16 + lr;
            #pragma unroll
            for (int s = 0; s < 2; ++s)
                a[m][s] = *(const s8b*)&gta[u * 64 + s * 32 + lg * 8];
        }
    }
    __syncthreads();

    #pragma unroll
    for (int m = 0; m < 2; ++m)
        #pragma unroll
        for (int n = 0; n < 3; ++n) {
            f32x4 acc = {0.f, 0.f, 0.f, 0.f};
            #pragma unroll
            for (int s = 0; s < 2; ++s) {
                s8b bfr = *(const s8b*)&Bp[(n * 16 + lr) * 72 + s * 32 + lg * 8];
                acc = __builtin_amdgcn_mfma_f32_16x16x32_bf16(a[m][s], bfr, acc, 0, 0, 0);
            }
            const int col = n * 16 + lr;
            #pragma unroll
            for (int r = 0; r < 4; ++r) {
                const int u = wv * 32 + m * 16 + lg * 4 + r;
                if (col < 24) {
                    PrB[(size_t)bo * 3072 + (size_t)u * 24 + col] = __float2bfloat16(acc[r]);
                } else {
                    const int y = col - 24;
                    if (y > 0)
                        PiB[(size_t)bo * 2944 + (size_t)u * 23 + (y - 1)] = __float2bfloat16(acc[r]);
                }
            }
        }
}

// ---------------------------------------------------------------------------
// k_fused (MFMA, transposed D[o][v], all-table operands): inverse W-transform
// + skip + GELU + MLP + soft-gate.  Block = (b,u): 2048 blocks, 256 thr.
// Twiddle/weight frags = single 16B loads from L2-hot tables.
// ---------------------------------------------------------------------------
__global__ __launch_bounds__(256) void k_fused(const float* __restrict__ x,
                                               const BF* __restrict__ PrB,
                                               const BF* __restrict__ PiB,
                                               const BF* __restrict__ gTw,
                                               const BF* __restrict__ wkB,
                                               const BF* __restrict__ w1B,
                                               const BF* __restrict__ w2B,
                                               const float* __restrict__ b1,
                                               const float* __restrict__ b2,
                                               const float* __restrict__ gt,
                                               float* __restrict__ out) {
    __shared__ __align__(16) short Plds[64 * 72];    // P^T [o][k]
    __shared__ __align__(16) short H1s[128 * 72];    // h1 bf16 [v][o]
    __shared__ __align__(16) short Zls[128 * 40];    // z  bf16 [v][kh]

    const int tid  = threadIdx.x;
    const int b    = blockIdx.x >> 7;
    const int u    = blockIdx.x & 127;
    const int lane = tid & 63;
    const int wv   = tid >> 6;
    const int lr   = lane & 15;
    const int lg   = lane >> 4;
    const int vb   = wv * 32;
    const int b64  = b * 64;

    // ---- stage P^T: cols 0..23 = Pr y, 24 = 0 (Pi y=0), 25..47 = Pi y=1..23
    for (int i = tid; i < 1536; i += 256) {
        int o = i / 24, y = i - o * 24;
        Plds[o * 72 + y] = *(const short*)&PrB[(size_t)(b64 + o) * 3072 + (size_t)u * 24 + y];
    }
    for (int i = tid; i < 1472; i += 256) {
        int o = i / 23, y1 = i - o * 23;
        Plds[o * 72 + 25 + y1] = *(const short*)&PiB[(size_t)(b64 + o) * 2944 + (size_t)u * 23 + y1];
    }
    if (tid < 64) Plds[tid * 72 + 24] = 0;
    for (int i = tid; i < 1024; i += 256)
        Plds[(i >> 4) * 72 + 48 + (i & 15)] = 0;

    // ---- x B-frags (cols = v)
    s8b bx[2][2];
    {
        const float* xb = x + (size_t)b64 * 16384 + (size_t)u * 128;
        #pragma unroll
        for (int nv = 0; nv < 2; ++nv) {
            const int v = vb + nv * 16 + lr;
            #pragma unroll
            for (int s = 0; s < 2; ++s)
                #pragma unroll
                for (int j = 0; j < 8; ++j)
                    bx[nv][s][j] = f2bs(xb[(size_t)(s * 32 + lg * 8 + j) * 16384 + v]);
        }
    }

    // ---- twiddle B-frags from table (one 16B load each)
    s8b btw[2][2];
    {
        const short* gtw = (const short*)gTw;
        #pragma unroll
        for (int nv = 0; nv < 2; ++nv) {
            const int v = vb + nv * 16 + lr;
            #pragma unroll
            for (int s = 0; s < 2; ++s)
                btw[nv][s] = *(const s8b*)&gtw[v * 64 + s * 32 + lg * 8];
        }
    }
    __syncthreads();   // Plds staged

    const short* wkb = (const short*)wkB;
    const short* w1b = (const short*)w1B;
    const short* w2b = (const short*)w2B;

    // ---- GEMM 1+2: spec + skip, D[o][v]
    f32x4 acc[4][2];
    #pragma unroll
    for (int mo = 0; mo < 4; ++mo)
        #pragma unroll
        for (int nv = 0; nv < 2; ++nv)
            #pragma unroll
            for (int r = 0; r < 4; ++r) acc[mo][nv][r] = 0.f;

    #pragma unroll
    for (int s = 0; s < 2; ++s)
        #pragma unroll
        for (int mo = 0; mo < 4; ++mo) {
            s8b ap = *(const s8b*)&Plds[(mo * 16 + lr) * 72 + s * 32 + lg * 8];
            #pragma unroll
            for (int nv = 0; nv < 2; ++nv)
                acc[mo][nv] = __builtin_amdgcn_mfma_f32_16x16x32_bf16(ap, btw[nv][s], acc[mo][nv], 0, 0, 0);
        }
    #pragma unroll
    for (int s = 0; s < 2; ++s)
        #pragma unroll
        for (int mo = 0; mo < 4; ++mo) {
            s8b aw = *(const s8b*)&wkb[(mo * 16 + lr) * 64 + s * 32 + lg * 8];
            #pragma unroll
            for (int nv = 0; nv < 2; ++nv)
                acc[mo][nv] = __builtin_amdgcn_mfma_f32_16x16x32_bf16(aw, bx[nv][s], acc[mo][nv], 0, 0, 0);
        }

    // ---- h1 = gelu(acc): element (o = mo*16+lg*4+r, v = vb+nv*16+lr)
    f32x4 h1r[4][2];
    #pragma unroll
    for (int mo = 0; mo < 4; ++mo)
        #pragma unroll
        for (int nv = 0; nv < 2; ++nv)
            #pragma unroll
            for (int r = 0; r < 4; ++r) {
                float h = geluf(acc[mo][nv][r]);
                h1r[mo][nv][r] = h;
                H1s[(vb + nv * 16 + lr) * 72 + mo * 16 + lg * 4 + r] = f2bs(h);
            }
    __syncthreads();   // H1 complete

    // ---- fc1: z^T[kh][v] = gelu(w1 @ h1^T + b1)
    f32x4 zac[2][2];
    #pragma unroll
    for (int mk = 0; mk < 2; ++mk)
        #pragma unroll
        for (int nv = 0; nv < 2; ++nv)
            #pragma unroll
            for (int r = 0; r < 4; ++r) zac[mk][nv][r] = 0.f;
    #pragma unroll
    for (int s = 0; s < 2; ++s) {
        s8b bh[2];
        #pragma unroll
        for (int nv = 0; nv < 2; ++nv)
            bh[nv] = *(const s8b*)&H1s[(vb + nv * 16 + lr) * 72 + s * 32 + lg * 8];
        #pragma unroll
        for (int mk = 0; mk < 2; ++mk) {
            s8b aw = *(const s8b*)&w1b[(mk * 16 + lr) * 64 + s * 32 + lg * 8];
            #pragma unroll
            for (int nv = 0; nv < 2; ++nv)
                zac[mk][nv] = __builtin_amdgcn_mfma_f32_16x16x32_bf16(aw, bh[nv], zac[mk][nv], 0, 0, 0);
        }
    }
    #pragma unroll
    for (int mk = 0; mk < 2; ++mk)
        #pragma unroll
        for (int r = 0; r < 4; ++r) {
            const float bb = b1[mk * 16 + lg * 4 + r];
            #pragma unroll
            for (int nv = 0; nv < 2; ++nv)
                Zls[(vb + nv * 16 + lr) * 40 + mk * 16 + lg * 4 + r] =
                    f2bs(geluf(zac[mk][nv][r] + bb));
        }
    __syncthreads();   // Zl complete

    // ---- fc2: out[o][v] = w2 @ z^T + b2 + gate*h1, K=32
    f32x4 oac[4][2];
    #pragma unroll
    for (int mo = 0; mo < 4; ++mo)
        #pragma unroll
        for (int nv = 0; nv < 2; ++nv)
            #pragma unroll
            for (int r = 0; r < 4; ++r) oac[mo][nv][r] = 0.f;
    s8b bz[2];
    #pragma unroll
    for (int nv = 0; nv < 2; ++nv)
        bz[nv] = *(const s8b*)&Zls[(vb + nv * 16 + lr) * 40 + lg * 8];
    #pragma unroll
    for (int mo = 0; mo < 4; ++mo) {
        s8b aw = *(const s8b*)&w2b[(mo * 16 + lr) * 32 + lg * 8];
        #pragma unroll
        for (int nv = 0; nv < 2; ++nv)
            oac[mo][nv] = __builtin_amdgcn_mfma_f32_16x16x32_bf16(aw, bz[nv], oac[mo][nv], 0, 0, 0);
    }

    // ---- epilogue: v-contiguous stores
    float* ob = out + (size_t)b64 * 16384 + (size_t)u * 128;
    #pragma unroll
    for (int mo = 0; mo < 4; ++mo)
        #pragma unroll
        for (int r = 0; r < 4; ++r) {
            const int o = mo * 16 + lg * 4 + r;
            const float b2v = b2[o];
            const float gv  = gt[o];
            #pragma unroll
            for (int nv = 0; nv < 2; ++nv)
                ob[(size_t)o * 16384 + vb + nv * 16 + lr] =
                    oac[mo][nv][r] + b2v + gv * h1r[mo][nv][r];
        }
}

// ---------------------------------------------------------------------------
extern "C" void kernel_launch(void* const* d_in, const int* in_sizes, int n_in,
                              void* d_out, int out_size, void* d_ws, size_t ws_size,
                              hipStream_t stream) {
    (void)in_sizes; (void)n_in; (void)out_size; (void)ws_size;
    const float* x   = (const float*)d_in[0];
    const float* wr  = (const float*)d_in[1];
    const float* wi  = (const float*)d_in[2];
    const float* wsk = (const float*)d_in[3];
    const float* w1  = (const float*)d_in[4];
    const float* b1  = (const float*)d_in[5];
    const float* w2  = (const float*)d_in[6];
    const float* b2  = (const float*)d_in[7];
    const float* gt  = (const float*)d_in[8];

    BF* wsB = (BF*)d_ws;
    BF* gB1 = wsB;                 // [0, 6144)        dead after k_fwd
    BF* gB2 = wsB + 6144;          // [6144, 18432)    dead after k_fwd
    BF* Sr  = wsB;                 // [0, 589824)      overwrites gB1/gB2 (legal)
    BF* Si  = wsB + 589824;        // [589824, 1179648)
    BF* Pr  = wsB + 1179648;       // [1179648, 4325376)
    BF* Pi  = wsB + 4325376;       // [4325376, 7340032)  23-plane; aliases X (X dead)
    BF* Xr  = wsB + 6160384;       // [6160384, 6750208)  dead after k_mix
    BF* Xi  = wsB + 6750208;       // [6750208, 7340032)
    BF* gTw = wsB + 7340032;       // [7340032, 7348224)  live whole run
    BF* gTa = wsB + 7348224;       // [7348224, 7356416)
    BF* wkB = wsB + 7356416;       // [7356416, 7360512)
    BF* w1B = wsB + 7360512;       // [7360512, 7362560)
    BF* w2B = wsB + 7362560;       // [7362560, 7364608)
    // peak footprint: 7364608 bf16 = 14.73 MB (< previous 14.94 MB)

    hipLaunchKernelGGL(k_tw,   dim3(168),  dim3(256), 0, stream,
                       wsk, w1, w2, gB1, gB2, gTw, gTa, wkB, w1B, w2B);
    hipLaunchKernelGGL(k_fwd,  dim3(1024), dim3(256), 0, stream, x, gB1, gB2, Xr, Xi);
    hipLaunchKernelGGL(k_mix,  dim3(576),  dim3(256), 0, stream, wr, wi, Xr, Xi, Sr, Si);
    hipLaunchKernelGGL(k_invP, dim3(1024), dim3(256), 0, stream, Sr, Si, gTa, Pr, Pi);
    hipLaunchKernelGGL(k_fused, dim3(2048), dim3(256), 0, stream,
                       x, Pr, Pi, gTw, wkB, w1B, w2B, b1, b2, gt, (float*)d_out);
}